// Round 6
// baseline (53.366 us; speedup 1.0000x reference)
//
#include <hip/hip_runtime.h>

// Per-class k-th order statistic (quantile) for Logit_Linear.get_th.
// 3-dispatch pipeline (cross-block handoff ONLY at kernel boundaries —
// in-kernel grid sync measured at ~70us/phase on MI355X, rounds 3-4):
//  K1 count:   64 blocks, per-block per-class counts (LDS) + block max.
//  K2 scatter: 64 blocks (same slices -> same-XCD L2 reuse): counting-sort
//              keys into contiguous per-class segments. Class bases computed
//              redundantly per block from the tiny counts matrix (32 KB).
//  K3 final:   1 block/class: stage segment in LDS, 4x8-bit radix select.
//              Hot-bin LDS atomics avoided via wave match-ballot aggregation.

#define MAXC      128        // supports class_num <= 128 (problem: 100)
#define NB        64         // K1/K2 blocks (same slicing!)
#define T1        1024
#define STAGE_CAP 12288      // segment staged in LDS in K3 (48 KB)
#define KEY_CAP   (1u << 21) // key buffer words (covers n <= 2M)

__device__ unsigned int g_counts[NB * MAXC];   // [block][class]
__device__ unsigned int g_blockmax[NB];
__device__ unsigned int g_keys[KEY_CAP];       // class-sorted fkey values

__device__ __forceinline__ unsigned int fkey(float f) {
    unsigned int u = __float_as_uint(f);
    return (u & 0x80000000u) ? ~u : (u | 0x80000000u);
}
__device__ __forceinline__ float ikey(unsigned int u) {
    unsigned int b = (u & 0x80000000u) ? (u ^ 0x80000000u) : ~u;
    return __uint_as_float(b);
}

// ------------------------------------------------------------------- K1 ----
__global__ __launch_bounds__(T1) void count_kernel(const float* __restrict__ score,
                                                   const int* __restrict__ label,
                                                   int n) {
    __shared__ unsigned int cnt[MAXC];
    __shared__ unsigned int wmax[T1 / 64];
    for (int i = threadIdx.x; i < MAXC; i += T1) cnt[i] = 0u;
    __syncthreads();

    const int per = ((n + NB - 1) / NB + 3) & ~3;
    const int i0 = blockIdx.x * per;
    const int i1 = min(n, i0 + per);
    const int nv = (i1 > i0) ? ((i1 - i0) >> 2) : 0;
    const float4* s4 = (const float4*)(score + i0);
    const int4*   l4 = (const int4*)(label + i0);
    unsigned int lmax = 0u;

    for (int j = threadIdx.x; j < nv; j += T1) {
        float4 s = s4[j]; int4 l = l4[j];
        float sv[4] = {s.x, s.y, s.z, s.w};
        int   lv[4] = {l.x, l.y, l.z, l.w};
#pragma unroll
        for (int q = 0; q < 4; ++q) {
            unsigned int u = fkey(sv[q]);
            lmax = lmax > u ? lmax : u;
            atomicAdd(&cnt[lv[q] & (MAXC - 1)], 1u);
        }
    }
    for (int i = i0 + (nv << 2) + threadIdx.x; i < i1; i += T1) {
        unsigned int u = fkey(score[i]);
        lmax = lmax > u ? lmax : u;
        atomicAdd(&cnt[label[i] & (MAXC - 1)], 1u);
    }
#pragma unroll
    for (int off = 32; off; off >>= 1) {
        unsigned int o = (unsigned int)__shfl_xor((int)lmax, off, 64);
        lmax = lmax > o ? lmax : o;
    }
    if ((threadIdx.x & 63) == 0) wmax[threadIdx.x >> 6] = lmax;
    __syncthreads();
    if (threadIdx.x == 0) {
        unsigned int m = wmax[0];
        for (int w = 1; w < T1 / 64; ++w) m = m > wmax[w] ? m : wmax[w];
        g_blockmax[blockIdx.x] = m;
    }
    for (int i = threadIdx.x; i < MAXC; i += T1)
        g_counts[blockIdx.x * MAXC + i] = cnt[i];
}

// ------------------------------------------------------------------- K2 ----
__global__ __launch_bounds__(T1) void scatter_kernel(const float* __restrict__ score,
                                                     const int* __restrict__ label,
                                                     int n) {
    __shared__ unsigned int base[MAXC];   // final write base per class
    __shared__ unsigned int cur[MAXC];    // local cursor per class
    __shared__ unsigned int tot[MAXC];    // scan array
    __shared__ unsigned int tota[MAXC];   // original totals
    const int t = threadIdx.x;
    const int b = blockIdx.x;

    if (t < MAXC) {
        unsigned int total = 0u, before = 0u;
        for (int bb = 0; bb < NB; ++bb) {
            unsigned int v = g_counts[bb * MAXC + t];
            total += v;
            if (bb < b) before += v;
        }
        tot[t] = total; tota[t] = total;
        base[t] = before;
        cur[t] = 0u;
    }
    __syncthreads();
    for (int off = 1; off < MAXC; off <<= 1) {   // inclusive scan of totals
        unsigned int add = (t < MAXC && t >= off) ? tot[t - off] : 0u;
        __syncthreads();
        if (t < MAXC) tot[t] += add;
        __syncthreads();
    }
    if (t < MAXC) base[t] += tot[t] - tota[t];   // + exclusive class base
    __syncthreads();

    const int per = ((n + NB - 1) / NB + 3) & ~3;
    const int i0 = b * per;
    const int i1 = min(n, i0 + per);
    const int nv = (i1 > i0) ? ((i1 - i0) >> 2) : 0;
    const float4* s4 = (const float4*)(score + i0);
    const int4*   l4 = (const int4*)(label + i0);

    for (int j = t; j < nv; j += T1) {
        float4 s = s4[j]; int4 l = l4[j];
        float sv[4] = {s.x, s.y, s.z, s.w};
        int   lv[4] = {l.x, l.y, l.z, l.w};
#pragma unroll
        for (int q = 0; q < 4; ++q) {
            unsigned int u = fkey(sv[q]);
            int c = lv[q] & (MAXC - 1);
            unsigned int pos = base[c] + atomicAdd(&cur[c], 1u);
            g_keys[pos] = u;
        }
    }
    for (int i = i0 + (nv << 2) + t; i < i1; i += T1) {
        unsigned int u = fkey(score[i]);
        int c = label[i] & (MAXC - 1);
        unsigned int pos = base[c] + atomicAdd(&cur[c], 1u);
        g_keys[pos] = u;
    }
}

// ------------------------------------------------------------------- K3 ----
__global__ __launch_bounds__(T1) void final_kernel(const int* __restrict__ cnp,
                                                   const int* __restrict__ epsp,
                                                   float* __restrict__ out) {
    int cn = *cnp; if (cn > MAXC) cn = MAXC;
    const int c = blockIdx.x;
    if (c >= cn) return;
    const int t = threadIdx.x;
    __shared__ unsigned int tot[MAXC];
    __shared__ unsigned int tota[MAXC];
    __shared__ unsigned int hist[256];
    __shared__ unsigned int scn[256];
    __shared__ unsigned int sel[2];
    __shared__ unsigned int stage[STAGE_CAP];

    if (t < MAXC) {
        unsigned int total = 0u;
        for (int bb = 0; bb < NB; ++bb) total += g_counts[bb * MAXC + t];
        tot[t] = total; tota[t] = total;
    }
    __syncthreads();
    for (int off = 1; off < MAXC; off <<= 1) {
        unsigned int add = (t < MAXC && t >= off) ? tot[t - off] : 0u;
        __syncthreads();
        if (t < MAXC) tot[t] += add;
        __syncthreads();
    }
    __syncthreads();

    const unsigned int m = tota[c];
    const unsigned int segbase = tot[c] - tota[c];
    // replicate JAX/NumPy weak-typed f32 arithmetic (verified exact, r1-r5)
    double eps = (double)(*epsp) / 100.0;
    float fac = (float)(1.0 - eps);
    int k = (int)((float)m * fac);
    if (m == 0u || k >= (int)m) {   // empty class: global max score
        if (t == 0) {
            unsigned int mx = 0u;
            for (int i = 0; i < NB; ++i) { unsigned int x = g_blockmax[i]; mx = x > mx ? x : mx; }
            out[c] = ikey(mx);
        }
        return;
    }

    const unsigned int* src;
    if (m <= STAGE_CAP) {
        for (unsigned int j = t; j < m; j += T1) stage[j] = g_keys[segbase + j];
        __syncthreads();
        src = stage;
    } else {
        src = &g_keys[segbase];
        __syncthreads();
    }

    int rem = k;
    unsigned int pref = 0u;
    const unsigned int mr = ((m + T1 - 1) / T1) * T1;  // all lanes iterate equally
    for (int shift = 24; shift >= 0; shift -= 8) {
        if (t < 256) hist[t] = 0u;
        __syncthreads();
        for (unsigned int j = t; j < mr; j += T1) {
            int valid = 0; unsigned int digit = 0u;
            if (j < m) {
                unsigned int u = src[j];
                if (shift == 24 || (u >> (shift + 8)) == (pref >> (shift + 8))) {
                    valid = 1; digit = (u >> shift) & 255u;
                }
            }
            // wave match-ballot aggregation: one atomic per distinct digit/wave
            unsigned long long vm = __ballot(valid);
            unsigned long long mm = vm;
#pragma unroll
            for (int bit = 0; bit < 8; ++bit) {
                unsigned long long bb = __ballot((int)((digit >> bit) & 1u));
                mm &= ((digit >> bit) & 1u) ? bb : ~bb;
            }
            if (valid) {
                int lead = __ffsll((long long)mm) - 1;
                if ((t & 63) == lead) atomicAdd(&hist[digit], (unsigned int)__popcll(mm));
            }
        }
        __syncthreads();
        if (t < 256) scn[t] = hist[t];
        __syncthreads();
        for (int off = 1; off < 256; off <<= 1) {
            unsigned int add = (t < 256 && t >= off) ? scn[t - off] : 0u;
            __syncthreads();
            if (t < 256) scn[t] += add;
            __syncthreads();
        }
        if (t < 256) {
            unsigned int incl = scn[t], excl = incl - hist[t];
            if ((unsigned)rem >= excl && (unsigned)rem < incl) { sel[0] = (unsigned)t; sel[1] = excl; }
        }
        __syncthreads();
        rem -= (int)sel[1];
        pref |= sel[0] << shift;
        __syncthreads();
    }
    if (t == 0) out[c] = ikey(pref);
}

extern "C" void kernel_launch(void* const* d_in, const int* in_sizes, int n_in,
                              void* d_out, int out_size, void* d_ws, size_t ws_size,
                              hipStream_t stream) {
    const float* score = (const float*)d_in[0];
    const int*   label = (const int*)d_in[1];
    const int*   cnp   = (const int*)d_in[2];
    const int*   epsp  = (const int*)d_in[3];
    float*       out   = (float*)d_out;
    int n = in_sizes[0];

    count_kernel  <<<NB,   T1, 0, stream>>>(score, label, n);
    scatter_kernel<<<NB,   T1, 0, stream>>>(score, label, n);
    final_kernel  <<<MAXC, T1, 0, stream>>>(cnp, epsp, out);
}

// Round 7
// 49.184 us; speedup vs baseline: 1.0850x; 1.0850x over previous
//
#include <hip/hip_runtime.h>

// Per-class k-th order statistic (quantile) for Logit_Linear.get_th.
// 2-dispatch pipeline (cross-block handoff ONLY at kernel boundaries —
// in-kernel grid sync measured at ~70us/phase on MI355X, rounds 3-4):
//  K1 sort:   256 blocks; slice (~3.9K elems) lives entirely in LDS:
//             load coalesced -> per-class count -> in-block exclusive
//             offsets -> LDS->LDS counting-sort -> ONE coalesced contiguous
//             flush of the class-sorted slice + per-block offset table +
//             block max. No global atomics, no uncoalesced stores.
//  K2 select: 1 block/class; class segment = 256 known-position runs;
//             binary-search gather (~10K words) into LDS; 4x8-bit radix
//             select with wave match-ballot aggregation (no hot-bin LDS
//             atomic serialization). Empty class -> global max.

#define MAXC      128         // supports class_num <= 128 (problem: 100)
#define NB        256         // K1 blocks (1 per CU)
#define T1        1024
#define SLICE_CAP 4096        // per-block slice capacity (n <= ~1.048M)
#define STAGE_CAP 12288       // class stage in K2 (48 KB)
#define SORT_CAP  (1u << 21)

__device__ unsigned int g_sorted[SORT_CAP];      // class-sorted keys, per-block
__device__ unsigned int g_off[NB * (MAXC + 1)];  // per-block class offsets
__device__ unsigned int g_blockmax[NB];

__device__ __forceinline__ unsigned int fkey(float f) {
    unsigned int u = __float_as_uint(f);
    return (u & 0x80000000u) ? ~u : (u | 0x80000000u);
}
__device__ __forceinline__ float ikey(unsigned int u) {
    unsigned int b = (u & 0x80000000u) ? (u ^ 0x80000000u) : ~u;
    return __uint_as_float(b);
}

// ------------------------------------------------------------------- K1 ----
__global__ __launch_bounds__(T1) void sort_kernel(const float* __restrict__ score,
                                                  const int* __restrict__ label,
                                                  int n) {
    __shared__ unsigned int  raw[SLICE_CAP];     // 16 KB: unsorted keys
    __shared__ unsigned int  skey[SLICE_CAP];    // 16 KB: sorted keys
    __shared__ unsigned char lab[SLICE_CAP];     // 4 KB
    __shared__ unsigned int  cnt[MAXC];
    __shared__ unsigned int  scn[MAXC];
    __shared__ unsigned int  exc[MAXC];
    __shared__ unsigned int  cur[MAXC];
    __shared__ unsigned int  wmax[T1 / 64];
    const int t = threadIdx.x;
    const int b = blockIdx.x;

    if (t < MAXC) cnt[t] = 0u;
    __syncthreads();

    const int per = ((n + NB - 1) / NB + 3) & ~3;
    const int i0 = b * per;
    const int i1 = min(n, i0 + per);
    const int len = (i1 > i0) ? (i1 - i0) : 0;
    const int nv = len >> 2;
    const float4* s4 = (const float4*)(score + i0);
    const int4*   l4 = (const int4*)(label + i0);
    unsigned int lmax = 0u;

    // single coalesced read: keys+labels into LDS, count classes
    for (int j = t; j < nv; j += T1) {
        float4 s = s4[j]; int4 l = l4[j];
        float sv[4] = {s.x, s.y, s.z, s.w};
        int   lv[4] = {l.x, l.y, l.z, l.w};
#pragma unroll
        for (int q = 0; q < 4; ++q) {
            unsigned int u = fkey(sv[q]);
            int c = lv[q] & (MAXC - 1);
            int idx = 4 * j + q;
            raw[idx] = u;
            lab[idx] = (unsigned char)c;
            lmax = lmax > u ? lmax : u;
            atomicAdd(&cnt[c], 1u);
        }
    }
    for (int i = (nv << 2) + t; i < len; i += T1) {
        unsigned int u = fkey(score[i0 + i]);
        int c = label[i0 + i] & (MAXC - 1);
        raw[i] = u;
        lab[i] = (unsigned char)c;
        lmax = lmax > u ? lmax : u;
        atomicAdd(&cnt[c], 1u);
    }
#pragma unroll
    for (int off = 32; off; off >>= 1) {
        unsigned int o = (unsigned int)__shfl_xor((int)lmax, off, 64);
        lmax = lmax > o ? lmax : o;
    }
    if ((t & 63) == 0) wmax[t >> 6] = lmax;
    __syncthreads();

    // exclusive scan of per-class counts -> block-local class offsets
    if (t < MAXC) scn[t] = cnt[t];
    __syncthreads();
    for (int off = 1; off < MAXC; off <<= 1) {
        unsigned int add = (t < MAXC && t >= off) ? scn[t - off] : 0u;
        __syncthreads();
        if (t < MAXC) scn[t] += add;
        __syncthreads();
    }
    if (t < MAXC) { exc[t] = scn[t] - cnt[t]; cur[t] = scn[t] - cnt[t]; }
    __syncthreads();

    // LDS->LDS counting-sort scatter (order within class irrelevant)
    for (int j = t; j < len; j += T1) {
        int c = lab[j];
        unsigned int p = atomicAdd(&cur[c], 1u);
        skey[p] = raw[j];
    }
    __syncthreads();

    // fully coalesced contiguous flush
    for (int j = t; j < len; j += T1) g_sorted[i0 + j] = skey[j];
    if (t < MAXC) g_off[b * (MAXC + 1) + t] = exc[t];
    if (t == 0) {
        g_off[b * (MAXC + 1) + MAXC] = (unsigned int)len;
        unsigned int m = wmax[0];
        for (int w = 1; w < T1 / 64; ++w) m = m > wmax[w] ? m : wmax[w];
        g_blockmax[b] = m;
    }
}

// ------------------------------------------------------------------- K2 ----
__device__ __forceinline__ int findrun(const unsigned int* pre, unsigned int f) {
    int lo = 0, hi = NB;              // invariant: pre[lo] <= f < pre[hi]
    while (hi - lo > 1) {
        int mid = (lo + hi) >> 1;
        if (pre[mid] <= f) lo = mid; else hi = mid;
    }
    return lo;
}

__global__ __launch_bounds__(T1) void select_kernel(const int* __restrict__ cnp,
                                                    const int* __restrict__ epsp,
                                                    float* __restrict__ out, int n) {
    int cn = *cnp; if (cn > MAXC) cn = MAXC;
    const int c = blockIdx.x;
    if (c >= cn) return;
    const int t = threadIdx.x;
    __shared__ unsigned int src_[NB];
    __shared__ unsigned int pre[NB + 1];
    __shared__ unsigned int hist[256];
    __shared__ unsigned int scn[256];
    __shared__ unsigned int sel[2];
    __shared__ unsigned int stage[STAGE_CAP];

    const int per = ((n + NB - 1) / NB + 3) & ~3;

    // run table: class c has one run per source block at a known position
    unsigned int mylen = 0u;
    if (t < NB) {
        unsigned int o0 = g_off[t * (MAXC + 1) + c];
        unsigned int o1 = g_off[t * (MAXC + 1) + c + 1];
        mylen = o1 - o0;
        src_[t] = (unsigned int)(t * per) + o0;
        pre[t] = mylen;
    }
    __syncthreads();
    for (int off = 1; off < NB; off <<= 1) {  // inclusive scan of run lengths
        unsigned int add = (t < NB && t >= off) ? pre[t - off] : 0u;
        __syncthreads();
        if (t < NB) pre[t] += add;
        __syncthreads();
    }
    if (t < NB) {
        unsigned int incl = pre[t];
        __syncthreads();
        pre[t + 1] = incl;          // shift to exclusive form: pre[0..NB]
        if (t == 0) pre[0] = 0u;
    } else {
        __syncthreads();
    }
    __syncthreads();
    const unsigned int m = pre[NB];

    // replicate JAX/NumPy weak-typed f32 arithmetic (verified exact, r1-r6)
    double eps = (double)(*epsp) / 100.0;
    float fac = (float)(1.0 - eps);
    int k = (int)((float)m * fac);

    if (m == 0u || k >= (int)m) {   // empty class: global max score
        hist[t & 255] = 0u;
        __syncthreads();
        if (t < NB) { unsigned int v = g_blockmax[t]; atomicMax(&hist[t & 255], v); }
        __syncthreads();
        for (int off = 128; off; off >>= 1) {
            if (t < off) { unsigned int a = hist[t + off]; if (a > hist[t]) hist[t] = a; }
            __syncthreads();
        }
        if (t == 0) out[c] = ikey(hist[0]);
        return;
    }

    const int staged = (m <= STAGE_CAP);
    if (staged) {
        for (unsigned int f = t; f < m; f += T1) {
            int sb = findrun(pre, f);
            stage[f] = g_sorted[src_[sb] + (f - pre[sb])];
        }
        __syncthreads();
    }

    int rem = k;
    unsigned int pref = 0u;
    const unsigned int mr = ((m + T1 - 1) / T1) * T1;
    for (int shift = 24; shift >= 0; shift -= 8) {
        if (t < 256) hist[t] = 0u;
        __syncthreads();
        for (unsigned int f = t; f < mr; f += T1) {
            int valid = 0; unsigned int digit = 0u;
            if (f < m) {
                unsigned int u;
                if (staged) u = stage[f];
                else { int sb = findrun(pre, f); u = g_sorted[src_[sb] + (f - pre[sb])]; }
                if (shift == 24 || (u >> (shift + 8)) == (pref >> (shift + 8))) {
                    valid = 1; digit = (u >> shift) & 255u;
                }
            }
            // wave match-ballot aggregation: one atomic per distinct digit/wave
            unsigned long long vm = __ballot(valid);
            unsigned long long mm = vm;
#pragma unroll
            for (int bit = 0; bit < 8; ++bit) {
                unsigned long long bb = __ballot((int)((digit >> bit) & 1u));
                mm &= ((digit >> bit) & 1u) ? bb : ~bb;
            }
            if (valid) {
                int lead = __ffsll((long long)mm) - 1;
                if ((t & 63) == lead) atomicAdd(&hist[digit], (unsigned int)__popcll(mm));
            }
        }
        __syncthreads();
        if (t < 256) scn[t] = hist[t];
        __syncthreads();
        for (int off = 1; off < 256; off <<= 1) {
            unsigned int add = (t < 256 && t >= off) ? scn[t - off] : 0u;
            __syncthreads();
            if (t < 256) scn[t] += add;
            __syncthreads();
        }
        if (t < 256) {
            unsigned int incl = scn[t], excl = incl - hist[t];
            if ((unsigned)rem >= excl && (unsigned)rem < incl) { sel[0] = (unsigned)t; sel[1] = excl; }
        }
        __syncthreads();
        rem -= (int)sel[1];
        pref |= sel[0] << shift;
        __syncthreads();
    }
    if (t == 0) out[c] = ikey(pref);
}

extern "C" void kernel_launch(void* const* d_in, const int* in_sizes, int n_in,
                              void* d_out, int out_size, void* d_ws, size_t ws_size,
                              hipStream_t stream) {
    const float* score = (const float*)d_in[0];
    const int*   label = (const int*)d_in[1];
    const int*   cnp   = (const int*)d_in[2];
    const int*   epsp  = (const int*)d_in[3];
    float*       out   = (float*)d_out;
    int n = in_sizes[0];

    sort_kernel  <<<NB,   T1, 0, stream>>>(score, label, n);
    select_kernel<<<MAXC, T1, 0, stream>>>(cnp, epsp, out, n);
}